// Round 9
// baseline (204.550 us; speedup 1.0000x reference)
//
#include <hip/hip_runtime.h>
#include <hip/hip_bf16.h>

#define BCNT 128
#define NNODE 64
#define HDIM 256
#define DDIM 128
#define KNEI 8
#define NR (BCNT * NNODE)
#define XPL 2097152ull   // ushorts per X plane: 64n * 8bt * 8kt * 512

typedef __attribute__((ext_vector_type(8))) short bf16x8;
typedef __attribute__((ext_vector_type(8))) unsigned short ushort8;
typedef __attribute__((ext_vector_type(4))) float f32x4;

__device__ __forceinline__ unsigned short f2bf(float f) {
    union { __hip_bfloat16 b; unsigned short u; } c;
    c.b = __float2bfloat16(f);
    return c.u;
}
__device__ __forceinline__ float bf2f(unsigned short u) {
    union { unsigned short u; __hip_bfloat16 b; } c;
    c.u = u;
    return __bfloat162float(c.b);
}
__device__ __forceinline__ void split2(float f, unsigned short& h, unsigned short& l) {
    h = f2bf(f);
    l = f2bf(f - bf2f(h));
}

// ---------------------------------------------------------------------------
// xsplit_frag: X[b][n][k] f32 -> 16-row frag-order bf16 hi/lo planes.
// plane[ ((n*8+bt)*8 + kt)*512 + lane*8 + i ]
//   = X[bt*16 + (lane&15)][n][kt*32 + (lane>>4)*8 + i]
// ---------------------------------------------------------------------------
__global__ __launch_bounds__(256) void xsplit_frag(
    const float* __restrict__ obs, const float* __restrict__ act,
    ushort* __restrict__ obsH, ushort* __restrict__ obsL,
    ushort* __restrict__ actH, ushort* __restrict__ actL)
{
    const int bx = blockIdx.x;
    const int n = bx >> 3, bt = bx & 7;
    const float* S = blockIdx.y ? act : obs;
    ushort* DH = blockIdx.y ? actH : obsH;
    ushort* DL = blockIdx.y ? actL : obsL;

    __shared__ float tile[16][257];
    const int t = threadIdx.x;
    {
        const int r = t >> 4, cs = (t & 15) * 16;
        const float* row = S + ((size_t)(bt * 16 + r) * NNODE + n) * HDIM + cs;
        #pragma unroll
        for (int j = 0; j < 4; ++j) {
            float4 v = *(const float4*)(row + j * 4);
            tile[r][cs + j * 4 + 0] = v.x;
            tile[r][cs + j * 4 + 1] = v.y;
            tile[r][cs + j * 4 + 2] = v.z;
            tile[r][cs + j * 4 + 3] = v.w;
        }
    }
    __syncthreads();
    const int kt = t >> 5, sub = t & 31;
    const int row = sub & 15;
    #pragma unroll
    for (int lg = 0; lg < 2; ++lg) {
        const int lane = lg * 32 + sub;
        const int kg = lane >> 4;
        ushort8 h8, l8;
        #pragma unroll
        for (int i = 0; i < 8; ++i) {
            unsigned short hh, ll;
            split2(tile[row][kt * 32 + kg * 8 + i], hh, ll);
            h8[i] = hh; l8[i] = ll;
        }
        size_t idx = ((((size_t)n * 8 + bt) * 8 + kt) * 512) + (size_t)lane * 8;
        *(ushort8*)(DH + idx) = h8;
        *(ushort8*)(DL + idx) = l8;
    }
}

// ---------------------------------------------------------------------------
// fused_mlp: mlp1 + LN/ReLU + mlp2, register-double-buffered prefetch in both
// GEMM phases (distance-1: next tile's X-frags + W f32 issued before current
// tile's convert+MFMA). 16x16x32 MFMA; W f32 loaded direct, split in-reg.
// Block 512 thr (8 waves) = 16 batch rows. Grid 1024; id = bt*128 + pair so
// the 8 bt-siblings of one (n,br) share an XCD (W panel L2 reuse).
// ---------------------------------------------------------------------------
__global__ __launch_bounds__(512, 4) void fused_mlp(
    const ushort* __restrict__ obsH, const ushort* __restrict__ obsL,
    const ushort* __restrict__ actH, const ushort* __restrict__ actL,
    const float* __restrict__ VW1, const float* __restrict__ AW1,
    const float* __restrict__ VW2, const float* __restrict__ AW2,
    const float* __restrict__ Vb1, const float* __restrict__ Ab1,
    const float* __restrict__ Vg1, const float* __restrict__ Vbe1,
    const float* __restrict__ Ag1, const float* __restrict__ Abe1,
    const float* __restrict__ Vb2, const float* __restrict__ Ab2,
    float* __restrict__ Vout, float* __restrict__ Aout)
{
    const int id = blockIdx.x;
    const int bt = id >> 7;
    const int pair = id & 127;
    const int n = pair >> 1, br = pair & 1;

    const int t = threadIdx.x;
    const int l = t & 63, w = t >> 6;
    const int l16 = l & 15, g4 = l >> 4;

    __shared__ ushort hbtH[16 * 264];
    __shared__ ushort hbtL[16 * 264];
    __shared__ float2 lnS[8][16];
    __shared__ float2 lnp[16];

    // ---- phase 1: h = X @ W1 (wave w -> out cols w*32..w*32+31) ----
    const float* W1n = br ? (AW1 + (size_t)n * 512 * HDIM)
                          : (VW1 + (size_t)n * 256 * HDIM);
    const int col0 = w * 32 + l16;
    const int col1 = w * 32 + 16 + l16;
    const size_t xbase = (((size_t)n * 8 + bt) * 8) * 512 + (size_t)l * 8;

    f32x4 aP0 = {}, aQ0 = {}, aP1 = {}, aQ1 = {};
    bf16x8 ahA, alA, ahB, alB;
    float w0A[8], w1A[8], w0B[8], w1B[8];

#define LX(kt_, XH_, XL_, AH_, AL_) { \
    const size_t xi_ = xbase + (size_t)(kt_) * 512; \
    AH_ = *(const bf16x8*)((XH_) + xi_); \
    AL_ = *(const bf16x8*)((XL_) + xi_); }

#define LW(wkt_, W0_, W1_) { \
    const float* wk_ = W1n + (size_t)((wkt_) * 32 + g4 * 8) * HDIM; \
    _Pragma("unroll") \
    for (int i_ = 0; i_ < 8; ++i_) { \
        W0_[i_] = wk_[(size_t)i_ * HDIM + col0]; \
        W1_[i_] = wk_[(size_t)i_ * HDIM + col1]; } }

#define FMA1(AH_, AL_, W0_, W1_) { \
    bf16x8 bh0_, bl0_, bh1_, bl1_; \
    _Pragma("unroll") \
    for (int i_ = 0; i_ < 8; ++i_) { \
        unsigned short h_, s_; \
        split2(W0_[i_], h_, s_); bh0_[i_] = (short)h_; bl0_[i_] = (short)s_; \
        split2(W1_[i_], h_, s_); bh1_[i_] = (short)h_; bl1_[i_] = (short)s_; } \
    aP0 = __builtin_amdgcn_mfma_f32_16x16x32_bf16(AH_, bh0_, aP0, 0, 0, 0); \
    aQ0 = __builtin_amdgcn_mfma_f32_16x16x32_bf16(AH_, bl0_, aQ0, 0, 0, 0); \
    aQ0 = __builtin_amdgcn_mfma_f32_16x16x32_bf16(AL_, bh0_, aQ0, 0, 0, 0); \
    aP1 = __builtin_amdgcn_mfma_f32_16x16x32_bf16(AH_, bh1_, aP1, 0, 0, 0); \
    aQ1 = __builtin_amdgcn_mfma_f32_16x16x32_bf16(AH_, bl1_, aQ1, 0, 0, 0); \
    aQ1 = __builtin_amdgcn_mfma_f32_16x16x32_bf16(AL_, bh1_, aQ1, 0, 0, 0); }

    LX(0, obsH, obsL, ahA, alA); LW(0, w0A, w1A);
    LX(1, obsH, obsL, ahB, alB); LW(1, w0B, w1B); FMA1(ahA, alA, w0A, w1A);
    LX(2, obsH, obsL, ahA, alA); LW(2, w0A, w1A); FMA1(ahB, alB, w0B, w1B);
    LX(3, obsH, obsL, ahB, alB); LW(3, w0B, w1B); FMA1(ahA, alA, w0A, w1A);
    LX(4, obsH, obsL, ahA, alA); LW(4, w0A, w1A); FMA1(ahB, alB, w0B, w1B);
    LX(5, obsH, obsL, ahB, alB); LW(5, w0B, w1B); FMA1(ahA, alA, w0A, w1A);
    LX(6, obsH, obsL, ahA, alA); LW(6, w0A, w1A); FMA1(ahB, alB, w0B, w1B);
    LX(7, obsH, obsL, ahB, alB); LW(7, w0B, w1B); FMA1(ahA, alA, w0A, w1A);
    if (!br) {
        FMA1(ahB, alB, w0B, w1B);
    } else {
        LX(0, actH, actL, ahA, alA); LW(8,  w0A, w1A); FMA1(ahB, alB, w0B, w1B);
        LX(1, actH, actL, ahB, alB); LW(9,  w0B, w1B); FMA1(ahA, alA, w0A, w1A);
        LX(2, actH, actL, ahA, alA); LW(10, w0A, w1A); FMA1(ahB, alB, w0B, w1B);
        LX(3, actH, actL, ahB, alB); LW(11, w0B, w1B); FMA1(ahA, alA, w0A, w1A);
        LX(4, actH, actL, ahA, alA); LW(12, w0A, w1A); FMA1(ahB, alB, w0B, w1B);
        LX(5, actH, actL, ahB, alB); LW(13, w0B, w1B); FMA1(ahA, alA, w0A, w1A);
        LX(6, actH, actL, ahA, alA); LW(14, w0A, w1A); FMA1(ahB, alB, w0B, w1B);
        LX(7, actH, actL, ahB, alB); LW(15, w0B, w1B); FMA1(ahA, alA, w0A, w1A);
        FMA1(ahB, alB, w0B, w1B);
    }
#undef LX
#undef LW
#undef FMA1

    // ---- phase 2: LN + ReLU + bf16 split -> LDS hbt ----
    const float* b1p = (br ? Ab1 : Vb1) + (size_t)n * HDIM;
    const float bc0 = b1p[col0], bc1 = b1p[col1];
    float v0[4], v1[4];
    {
        float s[4], q[4];
        #pragma unroll
        for (int j = 0; j < 4; ++j) {
            v0[j] = aP0[j] + aQ0[j] + bc0;
            v1[j] = aP1[j] + aQ1[j] + bc1;
            s[j] = v0[j] + v1[j];
            q[j] = v0[j] * v0[j] + v1[j] * v1[j];
        }
        #pragma unroll
        for (int off = 1; off < 16; off <<= 1) {
            #pragma unroll
            for (int j = 0; j < 4; ++j) {
                s[j] += __shfl_xor(s[j], off);
                q[j] += __shfl_xor(q[j], off);
            }
        }
        if (l16 == 0) {
            #pragma unroll
            for (int j = 0; j < 4; ++j) lnS[w][g4 * 4 + j] = float2{s[j], q[j]};
        }
    }
    __syncthreads();
    if (t < 16) {
        float ss = 0.f, qq = 0.f;
        #pragma unroll
        for (int w2 = 0; w2 < 8; ++w2) { ss += lnS[w2][t].x; qq += lnS[w2][t].y; }
        float mu = ss * (1.0f / 256.0f);
        float var = qq * (1.0f / 256.0f) - mu * mu;
        lnp[t] = float2{mu, rsqrtf(var + 1e-5f)};
    }
    __syncthreads();
    {
        const float* gp = br ? Ag1 : Vg1;
        const float* bep = br ? Abe1 : Vbe1;
        const float g0 = gp[col0], g1 = gp[col1];
        const float e0 = bep[col0], e1 = bep[col1];
        #pragma unroll
        for (int j = 0; j < 4; ++j) {
            const int row = g4 * 4 + j;
            float2 p = lnp[row];
            float y0 = fmaxf((v0[j] - p.x) * p.y * g0 + e0, 0.0f);
            float y1 = fmaxf((v1[j] - p.x) * p.y * g1 + e1, 0.0f);
            unsigned short hh, ll;
            split2(y0, hh, ll);
            hbtH[row * 264 + col0] = hh; hbtL[row * 264 + col0] = ll;
            split2(y1, hh, ll);
            hbtH[row * 264 + col1] = hh; hbtL[row * 264 + col1] = ll;
        }
    }
    __syncthreads();

    // ---- phase 3: out = hb @ W2 (wave w -> out cols w*16..w*16+15, full K) ----
    const float* W2n = (br ? AW2 : VW2) + (size_t)n * HDIM * DDIM;
    const int ocol = w * 16 + l16;
    f32x4 cP = {}, cQ = {};
    float w2A[8], w2B[8];

#define LH(kt_, AH_, AL_) { \
    const int lb_ = l16 * 264 + (kt_) * 32 + g4 * 8; \
    AH_ = *(const bf16x8*)&hbtH[lb_]; \
    AL_ = *(const bf16x8*)&hbtL[lb_]; }

#define LW2(kt_, W_) { \
    const float* wk_ = W2n + (size_t)((kt_) * 32 + g4 * 8) * DDIM; \
    _Pragma("unroll") \
    for (int i_ = 0; i_ < 8; ++i_) W_[i_] = wk_[(size_t)i_ * DDIM + ocol]; }

#define FMA3(AH_, AL_, W_) { \
    bf16x8 bh_, bl_; \
    _Pragma("unroll") \
    for (int i_ = 0; i_ < 8; ++i_) { \
        unsigned short h_, s_; \
        split2(W_[i_], h_, s_); bh_[i_] = (short)h_; bl_[i_] = (short)s_; } \
    cP = __builtin_amdgcn_mfma_f32_16x16x32_bf16(AH_, bh_, cP, 0, 0, 0); \
    cQ = __builtin_amdgcn_mfma_f32_16x16x32_bf16(AH_, bl_, cQ, 0, 0, 0); \
    cQ = __builtin_amdgcn_mfma_f32_16x16x32_bf16(AL_, bh_, cQ, 0, 0, 0); }

    LH(0, ahA, alA); LW2(0, w2A);
    LH(1, ahB, alB); LW2(1, w2B); FMA3(ahA, alA, w2A);
    LH(2, ahA, alA); LW2(2, w2A); FMA3(ahB, alB, w2B);
    LH(3, ahB, alB); LW2(3, w2B); FMA3(ahA, alA, w2A);
    LH(4, ahA, alA); LW2(4, w2A); FMA3(ahB, alB, w2B);
    LH(5, ahB, alB); LW2(5, w2B); FMA3(ahA, alA, w2A);
    LH(6, ahA, alA); LW2(6, w2A); FMA3(ahB, alB, w2B);
    LH(7, ahB, alB); LW2(7, w2B); FMA3(ahA, alA, w2A);
    FMA3(ahB, alB, w2B);
#undef LH
#undef LW2
#undef FMA3

    {
        const float b2 = (br ? Ab2 : Vb2)[(size_t)n * DDIM + ocol];
        float* outp = br ? Aout : Vout;
        #pragma unroll
        for (int j = 0; j < 4; ++j) {
            const int brow = bt * 16 + g4 * 4 + j;
            outp[((size_t)brow * NNODE + n) * DDIM + ocol] = cP[j] + cQ[j] + b2;
        }
    }
}

// ---------------------------------------------------------------------------
// chi for both Q=V+A and V; one block per (n, b), 128 threads = one per d
// ---------------------------------------------------------------------------
__global__ __launch_bounds__(128) void chi_kernel(
    const float* __restrict__ V, const float* __restrict__ A,
    const int* __restrict__ le, const float* __restrict__ m1,
    const float* __restrict__ m2, float* __restrict__ out)
{
    const int n = blockIdx.x;
    const int b = blockIdx.y;
    const int tid = threadIdx.x;

    __shared__ float sm1[KNEI];
    __shared__ float sm2[KNEI * KNEI];
    __shared__ int   sidx[KNEI + 1];
    __shared__ float pq[2], pv[2];

    if (tid < KNEI) {
        float s = 0.0f;
        #pragma unroll
        for (int hh = 0; hh < 3; ++hh) s += m1[n * 24 + hh * 8 + tid];
        sm1[tid] = s;
    }
    if (tid < 64) {
        int i = tid >> 3, j = tid & 7;
        float s = 0.0f;
        if (j > i) {
            #pragma unroll
            for (int hh = 0; hh < 3; ++hh) s += m2[n * 192 + hh * 64 + tid];
        }
        sm2[tid] = s;
    }
    if (tid < KNEI + 1) sidx[tid] = le[n * 18 + tid];
    __syncthreads();

    const float* Vb_ = V + (size_t)b * (NNODE * DDIM);
    const float* Ab_ = A + (size_t)b * (NNODE * DDIM);
    const int cen = sidx[0];

    float vn[KNEI], qn[KNEI];
    #pragma unroll
    for (int k = 0; k < KNEI; ++k) {
        int nb = sidx[1 + k];
        float vv = Vb_[nb * DDIM + tid];
        float aa = Ab_[nb * DDIM + tid];
        vn[k] = vv;
        qn[k] = vv + aa;
    }

    float sq = 0.0f, sv = 0.0f;
    #pragma unroll
    for (int k = 0; k < KNEI; ++k) { sq += sm1[k] * qn[k]; sv += sm1[k] * vn[k]; }
    #pragma unroll
    for (int i = 0; i < KNEI; ++i) {
        #pragma unroll
        for (int j = i + 1; j < KNEI; ++j) {
            float w = sm2[i * 8 + j];
            sq += w * fminf(qn[i], qn[j]);
            sv += w * fminf(vn[i], vn[j]);
        }
    }

    float Vc = Vb_[cen * DDIM + tid];
    float Ac = Ab_[cen * DDIM + tid];
    float valq = sq * (1.0f / 3.0f) + (Vc + Ac);
    float valv = sv * (1.0f / 3.0f) + Vc;

    #pragma unroll
    for (int o = 32; o; o >>= 1) {
        valq += __shfl_down(valq, o);
        valv += __shfl_down(valv, o);
    }
    if ((tid & 63) == 0) { pq[tid >> 6] = valq; pv[tid >> 6] = valv; }
    __syncthreads();
    if (tid == 0) {
        out[b * NNODE + n]                = (pq[0] + pq[1]) * (1.0f / 128.0f);
        out[BCNT * NNODE + b * NNODE + n] = (pv[0] + pv[1]) * (1.0f / 128.0f);
    }
}

extern "C" void kernel_launch(void* const* d_in, const int* in_sizes, int n_in,
                              void* d_out, int out_size, void* d_ws, size_t ws_size,
                              hipStream_t stream)
{
    const float* obs  = (const float*)d_in[0];
    const float* act  = (const float*)d_in[1];
    const int*   le   = (const int*)  d_in[2];
    const float* VW1  = (const float*)d_in[3];
    const float* Vb1  = (const float*)d_in[4];
    const float* Vg1  = (const float*)d_in[5];
    const float* Vbe1 = (const float*)d_in[6];
    const float* VW2  = (const float*)d_in[7];
    const float* Vb2  = (const float*)d_in[8];
    const float* AW1  = (const float*)d_in[9];
    const float* Ab1  = (const float*)d_in[10];
    const float* Ag1  = (const float*)d_in[11];
    const float* Abe1 = (const float*)d_in[12];
    const float* AW2  = (const float*)d_in[13];
    const float* Ab2  = (const float*)d_in[14];
    const float* m1   = (const float*)d_in[15];
    const float* m2   = (const float*)d_in[16];
    float* out = (float*)d_out;

    ushort* obsH = (ushort*)d_ws;
    ushort* obsL = obsH + XPL;
    ushort* actH = obsL + XPL;
    ushort* actL = actH + XPL;
    float*  V    = (float*)(actL + XPL);
    float*  A    = V + (size_t)NR * DDIM;

    xsplit_frag<<<dim3(512, 2), dim3(256), 0, stream>>>(obs, act, obsH, obsL, actH, actL);
    fused_mlp<<<dim3(1024), dim3(512), 0, stream>>>(obsH, obsL, actH, actL,
                                                    VW1, AW1, VW2, AW2,
                                                    Vb1, Ab1, Vg1, Vbe1, Ag1, Abe1,
                                                    Vb2, Ab2, V, A);
    chi_kernel<<<dim3(NNODE, BCNT), dim3(128), 0, stream>>>(V, A, le, m1, m2, out);
}